// Round 19
// baseline (201.553 us; speedup 1.0000x reference)
//
#include <hip/hip_runtime.h>
#include <hip/hip_bf16.h>
#include <cstdint>

// LSTM cell: B=8192, D=1024, U=1024.
// z = [X|H](8192x2048) @ Wcat(2048x4096), gate interleave 16 in N, fused epilogue.
// GEMM: 256x256 tile, BK=32, FOUR fat waves (2Mx2N), wave tile 128x128
// (acc 8x8 f32x4 = 256 VGPR, 1 wave/SIMD). LDS reads/window drop 96->64
// (below MFMA floor). Reads interleaved between MFMA groups (sched_barrier
// pins) so each wave self-hides LDS latency. 3 bufs, stage-ahead-2,
// vmcnt(8)+barrier per window. No setprio (R18: neutral-to-harmful).

using f32x4  = __attribute__((ext_vector_type(4))) float;
using short8 = __attribute__((ext_vector_type(8))) short;

__device__ __forceinline__ unsigned short f2bf(float f) {
  union { float f; unsigned int u; } v; v.f = f;
  unsigned int r = v.u + 0x7fffu + ((v.u >> 16) & 1u);  // RNE
  return (unsigned short)(r >> 16);
}
__device__ __forceinline__ float sigmoidf_fast(float x) { return 1.f / (1.f + __expf(-x)); }
__device__ __forceinline__ float tanhf_fast(float x)    { return 1.f - 2.f / (__expf(2.f * x) + 1.f); }

// ---------- A conversion: Abf[b][k] = bf16(k<1024 ? X[b][k] : H[b][k-1024])
__global__ void conv_a_kernel(const float* __restrict__ X, const float* __restrict__ H,
                              unsigned short* __restrict__ Abf) {
  int idx = blockIdx.x * blockDim.x + threadIdx.x;
  int b  = idx >> 8;
  int kq = (idx & 255) << 2;
  float4 x = *(const float4*)(X + (long)b * 1024 + kq);
  float4 h = *(const float4*)(H + (long)b * 1024 + kq);
  ushort4 xo, ho;
  xo.x = f2bf(x.x); xo.y = f2bf(x.y); xo.z = f2bf(x.z); xo.w = f2bf(x.w);
  ho.x = f2bf(h.x); ho.y = f2bf(h.y); ho.z = f2bf(h.z); ho.w = f2bf(h.w);
  *(ushort4*)(Abf + (long)b * 2048 + kq)        = xo;
  *(ushort4*)(Abf + (long)b * 2048 + 1024 + kq) = ho;
}

// ---------- B conversion: Bt[n][k] bf16, N-major, n = (u>>4)*64 + g*16 + (u&15)
__global__ void conv_b_kernel(const float* W_i, const float* U_i,
                              const float* W_f, const float* U_f,
                              const float* W_c, const float* U_c,
                              const float* W_o, const float* U_o,
                              unsigned short* __restrict__ Bt) {
  __shared__ float tile[64][65];
  int z = blockIdx.z;
  const float* src;
  switch (z) {
    case 0: src = W_i; break; case 1: src = U_i; break;
    case 2: src = W_f; break; case 3: src = U_f; break;
    case 4: src = W_c; break; case 5: src = U_c; break;
    case 6: src = W_o; break; default: src = U_o; break;
  }
  int g = z >> 1, s = z & 1;
  int k0 = blockIdx.x * 64;
  int u0 = blockIdx.y * 64;
  int t = threadIdx.x;
  int c = t & 63, r0 = t >> 6;
#pragma unroll
  for (int i = 0; i < 16; ++i) {
    int r = i * 4 + r0;
    tile[r][c] = src[(long)(k0 + r) * 1024 + u0 + c];
  }
  __syncthreads();
  int ul = t >> 2;
  int ks = (t & 3) * 16;
  unsigned short outv[16];
#pragma unroll
  for (int j = 0; j < 16; ++j) outv[j] = f2bf(tile[ks + j][ul]);
  long n   = 4L * u0 + (ul >> 4) * 64 + g * 16 + (ul & 15);
  long col = (long)s * 1024 + k0 + ks;
  uint4* dst = (uint4*)(Bt + n * 2048 + col);
  dst[0] = *(uint4*)(outv);
  dst[1] = *(uint4*)(outv + 8);
}

// ---------- fused GEMM + LSTM epilogue
// LDS buf (16384 shorts = 32KB): A[256][32] at +0, B[256][32] at +8192. 3 bufs.
__global__ __launch_bounds__(256, 1) void lstm_gemm_kernel(
    const unsigned short* __restrict__ Abf,   // [8192][2048] bf16
    const unsigned short* __restrict__ Btbf,  // [4096][2048] bf16 (N-major)
    const float* __restrict__ b_i, const float* __restrict__ b_f,
    const float* __restrict__ b_c, const float* __restrict__ b_o,
    const float* __restrict__ c_tm1,
    float* __restrict__ outH, float* __restrict__ outC) {
  __shared__ unsigned short smem[49152];  // 96KB

  int bid = blockIdx.x;
  int swz = (bid & 7) * 64 + (bid >> 3);  // XCD swizzle, 512 % 8 == 0
  int bm = swz >> 4;   // 32 m-blocks
  int bn = swz & 15;   // 16 n-blocks

  int t = threadIdx.x;      // 0..255
  int lane = t & 63;
  int w = t >> 6;           // 4 waves
  int wm = w >> 1;          // 0..1 (M half, 128 rows)
  int wn = w & 1;           // 0..1 (N half, 128 cols)
  int rl = lane & 15;
  int kg = lane >> 4;       // 0..3, 8-elem k-chunk

  // ---- frag ds_read offsets (XOR chunk swizzle: c ^= (row>>1)&3) ----
#define AOFFE(MI) ((wm * 128 + (MI) * 16 + rl) * 32 + \
    ((kg ^ (((wm * 128 + (MI) * 16 + rl) >> 1) & 3)) << 3))
#define BOFFE(NI) (8192 + (wn * 128 + (NI) * 16 + rl) * 32 + \
    ((kg ^ (((wn * 128 + (NI) * 16 + rl) >> 1) & 3)) << 3))
  const int offA0 = AOFFE(0), offA1 = AOFFE(1), offA2 = AOFFE(2), offA3 = AOFFE(3);
  const int offA4 = AOFFE(4), offA5 = AOFFE(5), offA6 = AOFFE(6), offA7 = AOFFE(7);
  const int offB0 = BOFFE(0), offB1 = BOFFE(1), offB2 = BOFFE(2), offB3 = BOFFE(3);
  const int offB4 = BOFFE(4), offB5 = BOFFE(5), offB6 = BOFFE(6), offB7 = BOFFE(7);
#undef AOFFE
#undef BOFFE

  // ---- staging (256 thr): line l covers rows l*64..l*64+63; thread t -> row
  // l*64 + (t>>2), chunk (t&3) inverse-swizzled. Dest = buf + l*2048 + t*8.
  int cbe = (((t & 3) ^ ((t >> 3) & 3))) << 3;   // ((l*64+(t>>2))>>1)&3 = (t>>3)&3
  const unsigned short* aS = Abf  + (long)(bm * 256 + (t >> 2)) * 2048 + cbe;
  const unsigned short* bS = Btbf + (long)(bn * 256 + (t >> 2)) * 2048 + cbe;
  const int dT = t * 8;

#define GLL(SRC, DELM)                                                                     \
  __builtin_amdgcn_global_load_lds((const __attribute__((address_space(1))) void*)(SRC),   \
      (__attribute__((address_space(3))) void*)(&smem[DELM]), 16, 0, 0)
  // stage one full tile (A 16KB + B 16KB) = 8 GLL lines
#define STAGE(SB, KOFF)                                                        \
  do {                                                                         \
    GLL(aS + (KOFF),          (SB) * 16384 + dT);                              \
    GLL(aS + 131072 + (KOFF), (SB) * 16384 + 2048 + dT);                       \
    GLL(aS + 262144 + (KOFF), (SB) * 16384 + 4096 + dT);                       \
    GLL(aS + 393216 + (KOFF), (SB) * 16384 + 6144 + dT);                       \
    GLL(bS + (KOFF),          (SB) * 16384 + 8192 + dT);                       \
    GLL(bS + 131072 + (KOFF), (SB) * 16384 + 10240 + dT);                      \
    GLL(bS + 262144 + (KOFF), (SB) * 16384 + 12288 + dT);                      \
    GLL(bS + 393216 + (KOFF), (SB) * 16384 + 14336 + dT);                      \
  } while (0)
#define VMC(N) asm volatile("s_waitcnt vmcnt(" #N ")" ::: "memory")
#define SB0()  __builtin_amdgcn_sched_barrier(0)

  f32x4 acc[8][8];
#pragma unroll
  for (int mi = 0; mi < 8; ++mi)
#pragma unroll
    for (int ni = 0; ni < 8; ++ni) acc[mi][ni] = (f32x4){0.f, 0.f, 0.f, 0.f};

  short8 aX, aY, bb0, bb1, bb2, bb3, bb4, bb5, bb6, bb7;

#define MFG(AF, MI)                                                                      \
  acc[MI][0] = __builtin_amdgcn_mfma_f32_16x16x32_bf16(AF, bb0, acc[MI][0], 0, 0, 0);    \
  acc[MI][1] = __builtin_amdgcn_mfma_f32_16x16x32_bf16(AF, bb1, acc[MI][1], 0, 0, 0);    \
  acc[MI][2] = __builtin_amdgcn_mfma_f32_16x16x32_bf16(AF, bb2, acc[MI][2], 0, 0, 0);    \
  acc[MI][3] = __builtin_amdgcn_mfma_f32_16x16x32_bf16(AF, bb3, acc[MI][3], 0, 0, 0);    \
  acc[MI][4] = __builtin_amdgcn_mfma_f32_16x16x32_bf16(AF, bb4, acc[MI][4], 0, 0, 0);    \
  acc[MI][5] = __builtin_amdgcn_mfma_f32_16x16x32_bf16(AF, bb5, acc[MI][5], 0, 0, 0);    \
  acc[MI][6] = __builtin_amdgcn_mfma_f32_16x16x32_bf16(AF, bb6, acc[MI][6], 0, 0, 0);    \
  acc[MI][7] = __builtin_amdgcn_mfma_f32_16x16x32_bf16(AF, bb7, acc[MI][7], 0, 0, 0);

// Window: read B frags + A0; stage tile w+2; then interleave {read a_{mi+1},
// 8 MFMA on a_mi} with sched_barrier pins; counted vmcnt(8); barrier.
#define WINDOW(RB, SB, KOFF, DOST, VMN, DOBAR)                                 \
  {                                                                            \
    const unsigned short* S_ = smem + (RB) * 16384;                            \
    bb0 = *(const short8*)(S_ + offB0);                                        \
    bb1 = *(const short8*)(S_ + offB1);                                        \
    bb2 = *(const short8*)(S_ + offB2);                                        \
    bb3 = *(const short8*)(S_ + offB3);                                        \
    bb4 = *(const short8*)(S_ + offB4);                                        \
    bb5 = *(const short8*)(S_ + offB5);                                        \
    bb6 = *(const short8*)(S_ + offB6);                                        \
    bb7 = *(const short8*)(S_ + offB7);                                        \
    aX  = *(const short8*)(S_ + offA0);                                        \
    if (DOST) STAGE(SB, KOFF);                                                 \
    SB0();                                                                     \
    aY = *(const short8*)(S_ + offA1); MFG(aX, 0) SB0();                       \
    aX = *(const short8*)(S_ + offA2); MFG(aY, 1) SB0();                       \
    aY = *(const short8*)(S_ + offA3); MFG(aX, 2) SB0();                       \
    aX = *(const short8*)(S_ + offA4); MFG(aY, 3) SB0();                       \
    aY = *(const short8*)(S_ + offA5); MFG(aX, 4) SB0();                       \
    aX = *(const short8*)(S_ + offA6); MFG(aY, 5) SB0();                       \
    aY = *(const short8*)(S_ + offA7); MFG(aX, 6) SB0();                       \
    MFG(aY, 7)                                                                 \
    if ((VMN) == 8) VMC(8);                                                    \
    if ((VMN) == 0) VMC(0);                                                    \
    if (DOBAR) __builtin_amdgcn_s_barrier();                                   \
  }

  // ---- prologue: stage tiles 0 -> buf0, 1 -> buf1; drain tile 0 only ----
  STAGE(0, 0);
  STAGE(1, 32);
  VMC(8);
  __builtin_amdgcn_s_barrier();
  aS += 64; bS += 64;   // source base -> tile 2

  // ---- windows 0..59 (stage tiles 2..61) ----
  for (int g = 0; g < 20; ++g) {
    WINDOW(0, 2, 0,  1, 8, 1);
    WINDOW(1, 0, 32, 1, 8, 1);
    WINDOW(2, 1, 64, 1, 8, 1);
    aS += 96; bS += 96;
  }
  // ---- tail: w60 stages t62, w61 stages t63, w62 drains, w63 pure ----
  WINDOW(0, 2, 0,  1, 8, 1);
  WINDOW(1, 0, 32, 1, 8, 1);
  WINDOW(2, 0, 0,  0, 0, 1);
  WINDOW(0, 0, 0,  0, -1, 0);
#undef WINDOW
#undef MFG
#undef SB0
#undef VMC
#undef STAGE
#undef GLL

  // ---- fused LSTM epilogue ----
  // Wave tile 128x128 = 8 mi x two u-16-blocks; gate = ni&3, ublock = ni>>2.
  // C/D layout: col = lane&15, row = (lane>>4)*4 + j.
  int mbase = bm * 256 + wm * 128;
  int nbase = bn * 256 + wn * 128;
  int ub = nbase >> 2;
  int u0 = ub + rl;
  int u1 = ub + 16 + rl;
  float bi0 = b_i[u0], bf0 = b_f[u0], bc0 = b_c[u0], bo0 = b_o[u0];
  float bi1 = b_i[u1], bf1 = b_f[u1], bc1 = b_c[u1], bo1 = b_o[u1];
  int rquad = kg << 2;
#pragma unroll
  for (int mi = 0; mi < 8; ++mi) {
#pragma unroll
    for (int j = 0; j < 4; ++j) {
      int brow = mbase + mi * 16 + rquad + j;
      {
        float zi = acc[mi][0][j] + bi0;
        float zf = acc[mi][1][j] + bf0;
        float zc = acc[mi][2][j] + bc0;
        float zo = acc[mi][3][j] + bo0;
        float ig = sigmoidf_fast(zi);
        float fg = sigmoidf_fast(zf);
        float cg = tanhf_fast(zc);
        float og = sigmoidf_fast(zo);
        float cp = c_tm1[(long)brow * 1024 + u0];
        float cn = fg * cp + ig * cg;
        float hn = og * tanhf_fast(cn);
        outH[(long)brow * 1024 + u0] = hn;
        outC[(long)brow * 1024 + u0] = cn;
      }
      {
        float zi = acc[mi][4][j] + bi1;
        float zf = acc[mi][5][j] + bf1;
        float zc = acc[mi][6][j] + bc1;
        float zo = acc[mi][7][j] + bo1;
        float ig = sigmoidf_fast(zi);
        float fg = sigmoidf_fast(zf);
        float cg = tanhf_fast(zc);
        float og = sigmoidf_fast(zo);
        float cp = c_tm1[(long)brow * 1024 + u1];
        float cn = fg * cp + ig * cg;
        float hn = og * tanhf_fast(cn);
        outH[(long)brow * 1024 + u1] = hn;
        outC[(long)brow * 1024 + u1] = cn;
      }
    }
  }
}

extern "C" void kernel_launch(void* const* d_in, const int* in_sizes, int n_in,
                              void* d_out, int out_size, void* d_ws, size_t ws_size,
                              hipStream_t stream) {
  (void)in_sizes; (void)n_in; (void)out_size; (void)ws_size;
  const float* X   = (const float*)d_in[0];
  const float* Hst = (const float*)d_in[1];
  const float* Cst = (const float*)d_in[2];
  const float* W_i = (const float*)d_in[3];
  const float* U_i = (const float*)d_in[4];
  const float* b_i = (const float*)d_in[5];
  const float* W_f = (const float*)d_in[6];
  const float* U_f = (const float*)d_in[7];
  const float* b_f = (const float*)d_in[8];
  const float* W_c = (const float*)d_in[9];
  const float* U_c = (const float*)d_in[10];
  const float* b_c = (const float*)d_in[11];
  const float* W_o = (const float*)d_in[12];
  const float* U_o = (const float*)d_in[13];
  const float* b_o = (const float*)d_in[14];

  unsigned short* Abf  = (unsigned short*)d_ws;                        // 32 MB
  unsigned short* Btbf = (unsigned short*)((char*)d_ws + 33554432);    // 16 MB

  float* outH = (float*)d_out;
  float* outC = outH + 8192L * 1024;

  conv_a_kernel<<<8192, 256, 0, stream>>>(X, Hst, Abf);
  conv_b_kernel<<<dim3(16, 16, 8), 256, 0, stream>>>(W_i, U_i, W_f, U_f, W_c, U_c, W_o, U_o, Btbf);
  lstm_gemm_kernel<<<512, 256, 0, stream>>>(Abf, Btbf, b_i, b_f, b_c, b_o, Cst, outH, outC);
}